// Round 8
// baseline (1511.276 us; speedup 1.0000x reference)
//
#include <hip/hip_runtime.h>

#define N_NODES 65536
#define N_EDGES 1048576
#define E_TOTAL (N_EDGES + N_NODES)
#define VOCAB 50000
#define HIDDEN 256
#define NUM_GRAPHS 64
#define NEG_SLOPE 0.2f
#define SM_EPS 1e-16f

typedef _Float16 f16x8 __attribute__((ext_vector_type(8)));
typedef _Float16 f16x4 __attribute__((ext_vector_type(4)));
typedef float f32x4 __attribute__((ext_vector_type(4)));

// ---------------- gather: x = (fp16) emb[nodes] ----------------
__global__ __launch_bounds__(256) void gather_kernel(const int* __restrict__ nodes,
    const float* __restrict__ emb, _Float16* __restrict__ x) {
    int i = blockIdx.x;
    int t = threadIdx.x;
    x[(size_t)i * HIDDEN + t] = (_Float16)emb[(size_t)nodes[i] * HIDDEN + t];
}

// ---------------- weight transpose+convert: WT[mat][n][k] = (fp16) W[mat][k][n] ----------------
__global__ __launch_bounds__(256) void convert_wt_kernel(const float* __restrict__ Wg,
    const float* __restrict__ Wl, _Float16* __restrict__ WT) {
    int mat = blockIdx.y;
    int n = blockIdx.x;
    int k = threadIdx.x;
    const float* W = (mat < 3) ? (Wg + (size_t)mat * HIDDEN * HIDDEN)
                               : (Wl + (size_t)(mat - 3) * HIDDEN * HIDDEN);
    WT[(size_t)mat * HIDDEN * HIDDEN + (size_t)n * HIDDEN + k] = (_Float16)W[(size_t)k * HIDDEN + n];
}

// ---------------- CSR build (by dst) ----------------
__global__ __launch_bounds__(256) void hist_kernel(const int* __restrict__ ei, int* __restrict__ counts) {
    int e = blockIdx.x * 256 + threadIdx.x;
    if (e >= E_TOTAL) return;
    int dst = (e < N_EDGES) ? ei[N_EDGES + e] : (e - N_EDGES);
    atomicAdd(&counts[dst], 1);
}

__global__ __launch_bounds__(1024) void scan_kernel(const int* __restrict__ counts,
    int* __restrict__ row_ptr, int* __restrict__ cursor) {
    __shared__ int sp[1024];
    int t = threadIdx.x;
    int base = t * 64;
    int s = 0;
    for (int i = 0; i < 64; i++) s += counts[base + i];
    sp[t] = s;
    __syncthreads();
    for (int d = 1; d < 1024; d <<= 1) {
        int v = (t >= d) ? sp[t - d] : 0;
        __syncthreads();
        sp[t] += v;
        __syncthreads();
    }
    int run = sp[t] - s;
    for (int i = 0; i < 64; i++) {
        int c = counts[base + i];
        row_ptr[base + i] = run;
        cursor[base + i] = run;
        run += c;
    }
    if (t == 1023) row_ptr[N_NODES] = run;
}

__global__ __launch_bounds__(256) void scatter_kernel(const int* __restrict__ ei,
    int* __restrict__ cursor, int* __restrict__ src_sorted) {
    int e = blockIdx.x * 256 + threadIdx.x;
    if (e >= E_TOTAL) return;
    int src, dst;
    if (e < N_EDGES) { src = ei[e]; dst = ei[N_EDGES + e]; }
    else             { src = dst = e - N_EDGES; }
    int pos = atomicAdd(&cursor[dst], 1);
    src_sorted[pos] = src;
}

// ---------------- fp16 MFMA GEMM (LDS-staged) + fused dots epilogue ----
#define PAD_K 40
__global__ __launch_bounds__(256) void gemm_f16_kernel(const _Float16* __restrict__ A,
    const _Float16* __restrict__ WT, const float* __restrict__ bias,
    _Float16* __restrict__ C,
    const float* __restrict__ a_s, const float* __restrict__ a_d,
    float* __restrict__ es, float* __restrict__ ed) {
    __shared__ _Float16 As[128][PAD_K];
    __shared__ _Float16 Bs[256][PAD_K];
    int tid = threadIdx.x;
    int wave = tid >> 6;
    int lane = tid & 63;
    int quad = lane >> 4;
    int l16 = lane & 15;
    int m0 = blockIdx.x * 128;

    f32x4 acc[2][16];
    #pragma unroll
    for (int rt = 0; rt < 2; rt++)
        #pragma unroll
        for (int ct = 0; ct < 16; ct++)
            acc[rt][ct] = (f32x4){0.f, 0.f, 0.f, 0.f};

    for (int k0 = 0; k0 < HIDDEN; k0 += 32) {
        __syncthreads();
        #pragma unroll
        for (int i = 0; i < 2; i++) {
            int c = tid + i * 256;
            int row = c >> 2, q = c & 3;
            *(f16x8*)&As[row][q * 8] =
                *(const f16x8*)(A + (size_t)(m0 + row) * HIDDEN + k0 + q * 8);
        }
        #pragma unroll
        for (int i = 0; i < 4; i++) {
            int c = tid + i * 256;
            int row = c >> 2, q = c & 3;
            *(f16x8*)&Bs[row][q * 8] =
                *(const f16x8*)(WT + (size_t)row * HIDDEN + k0 + q * 8);
        }
        __syncthreads();
        f16x8 a0 = *(const f16x8*)&As[wave * 32 + l16][quad * 8];
        f16x8 a1 = *(const f16x8*)&As[wave * 32 + 16 + l16][quad * 8];
        #pragma unroll
        for (int ct = 0; ct < 16; ct++) {
            f16x8 b = *(const f16x8*)&Bs[ct * 16 + l16][quad * 8];
            acc[0][ct] = __builtin_amdgcn_mfma_f32_16x16x32_f16(a0, b, acc[0][ct], 0, 0, 0);
            acc[1][ct] = __builtin_amdgcn_mfma_f32_16x16x32_f16(a1, b, acc[1][ct], 0, 0, 0);
        }
    }
    #pragma unroll
    for (int rt = 0; rt < 2; rt++) {
        #pragma unroll
        for (int ct = 0; ct < 16; ct++) {
            int col = ct * 16 + l16;
            float bv = (bias != nullptr) ? bias[col] : 0.f;
            int rowbase = m0 + wave * 32 + rt * 16 + quad * 4;
            #pragma unroll
            for (int r = 0; r < 4; r++) {
                C[(size_t)(rowbase + r) * HIDDEN + col] = (_Float16)(acc[rt][ct][r] + bv);
            }
        }
    }
    // fused dots: es/ed from fp32 acc
    if (es != nullptr) {
        #pragma unroll
        for (int rt = 0; rt < 2; rt++) {
            float ds0 = 0.f, ds1 = 0.f, ds2 = 0.f, ds3 = 0.f;
            float dd0 = 0.f, dd1 = 0.f, dd2 = 0.f, dd3 = 0.f;
            #pragma unroll
            for (int ct = 0; ct < 16; ct++) {
                int col = ct * 16 + l16;
                float av = a_s[col];
                float dv = a_d[col];
                ds0 += acc[rt][ct][0] * av; dd0 += acc[rt][ct][0] * dv;
                ds1 += acc[rt][ct][1] * av; dd1 += acc[rt][ct][1] * dv;
                ds2 += acc[rt][ct][2] * av; dd2 += acc[rt][ct][2] * dv;
                ds3 += acc[rt][ct][3] * av; dd3 += acc[rt][ct][3] * dv;
            }
            #pragma unroll
            for (int off = 1; off < 16; off <<= 1) {
                ds0 += __shfl_xor(ds0, off); dd0 += __shfl_xor(dd0, off);
                ds1 += __shfl_xor(ds1, off); dd1 += __shfl_xor(dd1, off);
                ds2 += __shfl_xor(ds2, off); dd2 += __shfl_xor(dd2, off);
                ds3 += __shfl_xor(ds3, off); dd3 += __shfl_xor(dd3, off);
            }
            if (l16 == 0) {
                int rowbase = m0 + wave * 32 + rt * 16 + quad * 4;
                es[rowbase + 0] = ds0; ed[rowbase + 0] = dd0;
                es[rowbase + 1] = ds1; ed[rowbase + 1] = dd1;
                es[rowbase + 2] = ds2; ed[rowbase + 2] = dd2;
                es[rowbase + 3] = ds3; ed[rowbase + 3] = dd3;
            }
        }
    }
}

// ---------------- softmax stats: per-edge w -> epack{src,w}, per-dst 1/denom ----
// No h traffic: es (256 KB) is L2-resident. Wave per dst.
__global__ __launch_bounds__(256) void stats_kernel(
    const int* __restrict__ row_ptr, const int* __restrict__ src_sorted,
    const float* __restrict__ es, const float* __restrict__ ed,
    int2* __restrict__ epack, float* __restrict__ dinv) {
    int gtid = blockIdx.x * 256 + threadIdx.x;
    int dst = gtid >> 6;
    int lane = threadIdx.x & 63;
    if (dst >= N_NODES) return;
    int start = row_ptr[dst];
    int end = row_ptr[dst + 1];
    float edd = ed[dst];

    // pass 1: e = leaky(es[src]+edd) -> epack{src,e}; segment max
    float m = -1e30f;
    for (int i = start + lane; i < end; i += 64) {
        int s = src_sorted[i];
        float e = es[s] + edd;
        e = (e > 0.f) ? e : NEG_SLOPE * e;
        epack[i] = make_int2(s, __float_as_int(e));
        m = fmaxf(m, e);
    }
    for (int off = 32; off; off >>= 1) m = fmaxf(m, __shfl_xor(m, off));

    // pass 2: w = exp(e-m) -> epack{src,w}; denom
    float denom = 0.f;
    for (int i = start + lane; i < end; i += 64) {
        int2 v = epack[i];
        float w = __expf(__int_as_float(v.y) - m);
        epack[i] = make_int2(v.x, __float_as_int(w));
        denom += w;
    }
    for (int off = 32; off; off >>= 1) denom += __shfl_xor(denom, off);
    if (lane == 0) dinv[dst] = 1.0f / (denom + SM_EPS);
}

// ---------------- XCD-affine column-sliced aggregate ----------------
// grid (8, N/4): slice s = blockIdx.x owns columns [s*32, s*32+32).
// With x-fastest dispatch and round-robin XCD assignment, XCD = s, so each
// XCD's L2 only ever touches a 4 MB column-slice of h (fits in 4 MB L2).
// Wave per dst; lane-halves process alternate edges; lane owns 1 column.
__global__ __launch_bounds__(256) void slice_agg_kernel(const _Float16* __restrict__ h,
    const int* __restrict__ row_ptr, const int2* __restrict__ epack,
    const float* __restrict__ dinv, const float* __restrict__ bg,
    _Float16* __restrict__ g) {
    int wave = threadIdx.x >> 6;
    int lane = threadIdx.x & 63;
    int dst = blockIdx.y * 4 + wave;
    int half = lane >> 5;           // 0/1: edge parity
    int col = blockIdx.x * 32 + (lane & 31);
    int start = row_ptr[dst];
    int end = row_ptr[dst + 1];

    float acc = 0.f;
    int i = start + half;
    // unroll x4: 4 outstanding 64B h-line loads per half
    for (; i + 6 < end; i += 8) {
        int2 m0 = epack[i];
        int2 m1 = epack[i + 2];
        int2 m2 = epack[i + 4];
        int2 m3 = epack[i + 6];
        float h0 = (float)h[(size_t)m0.x * HIDDEN + col];
        float h1 = (float)h[(size_t)m1.x * HIDDEN + col];
        float h2 = (float)h[(size_t)m2.x * HIDDEN + col];
        float h3 = (float)h[(size_t)m3.x * HIDDEN + col];
        acc += __int_as_float(m0.y) * h0 + __int_as_float(m1.y) * h1
             + __int_as_float(m2.y) * h2 + __int_as_float(m3.y) * h3;
    }
    for (; i < end; i += 2) {
        int2 m0 = epack[i];
        acc += __int_as_float(m0.y) * (float)h[(size_t)m0.x * HIDDEN + col];
    }
    // merge edge-parity halves (lane l and l^32 hold the same column)
    acc += __shfl_xor(acc, 32);
    float r = fmaxf(acc * dinv[dst] + bg[col], 0.f);
    if (half == 0) g[(size_t)dst * HIDDEN + col] = (_Float16)r;
}

// ---------------- graph boundaries: batch is SORTED -> binary search ----------------
__global__ __launch_bounds__(128) void graph_bounds_kernel(const int* __restrict__ batch,
    int* __restrict__ gstart) {
    int g = threadIdx.x;
    if (g > NUM_GRAPHS) return;
    if (g == NUM_GRAPHS) { gstart[NUM_GRAPHS] = N_NODES; return; }
    int lo = 0, hi = N_NODES;
    while (lo < hi) {
        int mid = (lo + hi) >> 1;
        if (batch[mid] < g) lo = mid + 1; else hi = mid;
    }
    gstart[g] = lo;
}

// ---------------- mean pool: owner-computes partial reduction (fp16 x) ----------------
#define POOL_SPLITS 16
__global__ __launch_bounds__(256) void pool_partial_kernel(const _Float16* __restrict__ x,
    const int* __restrict__ gstart, float* __restrict__ pooledT) {
    int g = blockIdx.x;
    int chunk = blockIdx.y;
    int t = threadIdx.x;
    int s = gstart[g];
    int e = gstart[g + 1];
    int n = e - s;
    int per = (n + POOL_SPLITS - 1) / POOL_SPLITS;
    int r0 = s + chunk * per;
    int r1 = min(r0 + per, e);
    if (r0 >= r1) return;
    float acc = 0.f;
    for (int r = r0; r < r1; r++) acc += (float)x[(size_t)r * HIDDEN + t];
    atomicAdd(&pooledT[t * NUM_GRAPHS + g], acc);
}

__global__ __launch_bounds__(256) void mean_kernel(const float* __restrict__ pooledT,
    const int* __restrict__ gstart, float* __restrict__ meanT) {
    int i = blockIdx.x * 256 + threadIdx.x;
    int g = i & (NUM_GRAPHS - 1);
    float c = (float)max(gstart[g + 1] - gstart[g], 1);
    meanT[i] = pooledT[i] / c;
}

// ---------------- final: out[64,50000] = pooled @ Wout + bout (fp32) ----------------
#define FINAL_GSPLIT 4
#define G_PER (NUM_GRAPHS / FINAL_GSPLIT)
__global__ __launch_bounds__(256) void final_kernel(const float* __restrict__ meanT,
    const float* __restrict__ Wout, const float* __restrict__ bout, float* __restrict__ out) {
    int j = blockIdx.x * 256 + threadIdx.x;
    int g0 = blockIdx.y * G_PER;
    if (j >= VOCAB) return;
    float acc[G_PER];
    #pragma unroll
    for (int g = 0; g < G_PER; g++) acc[g] = 0.f;
    #pragma unroll 4
    for (int k = 0; k < HIDDEN; k++) {
        float w = Wout[(size_t)k * VOCAB + j];
        #pragma unroll
        for (int g = 0; g < G_PER; g++) acc[g] += meanT[k * NUM_GRAPHS + g0 + g] * w;
    }
    float b = bout[j];
    #pragma unroll
    for (int g = 0; g < G_PER; g++) out[(size_t)(g0 + g) * VOCAB + j] = acc[g] + b;
}

extern "C" void kernel_launch(void* const* d_in, const int* in_sizes, int n_in,
                              void* d_out, int out_size, void* d_ws, size_t ws_size,
                              hipStream_t stream) {
    const int*   nodes = (const int*)d_in[0];
    const int*   ei    = (const int*)d_in[1];
    const int*   batch = (const int*)d_in[2];
    const float* emb   = (const float*)d_in[3];
    const float* Wg    = (const float*)d_in[4];
    const float* a_src = (const float*)d_in[5];
    const float* a_dst = (const float*)d_in[6];
    const float* bg    = (const float*)d_in[7];
    const float* Wl    = (const float*)d_in[8];
    const float* bl    = (const float*)d_in[9];
    const float* Wout  = (const float*)d_in[10];
    const float* bout  = (const float*)d_in[11];
    float* out = (float*)d_out;

    char* ws = (char*)d_ws;
    size_t off = 0;
    auto alloc = [&](size_t bytes) -> void* {
        void* p = ws + off;
        off += (bytes + 255) & ~(size_t)255;
        return p;
    };
    _Float16* bufA    = (_Float16*)alloc((size_t)N_NODES * HIDDEN * 2);
    _Float16* bufB    = (_Float16*)alloc((size_t)N_NODES * HIDDEN * 2);
    _Float16* WT      = (_Float16*)alloc((size_t)6 * HIDDEN * HIDDEN * 2);
    float* es         = (float*)alloc((size_t)N_NODES * 4);
    float* ed         = (float*)alloc((size_t)N_NODES * 4);
    int*   counts     = (int*)alloc((size_t)N_NODES * 4);
    int*   row_ptr    = (int*)alloc((size_t)(N_NODES + 1) * 4);
    int*   cursor     = (int*)alloc((size_t)N_NODES * 4);
    int*   src_sorted = (int*)alloc((size_t)E_TOTAL * 4);
    int2*  epack      = (int2*)alloc((size_t)E_TOTAL * 8);
    float* dinv       = (float*)alloc((size_t)N_NODES * 4);
    float* pooledT    = (float*)alloc((size_t)HIDDEN * NUM_GRAPHS * 4);
    float* meanT      = (float*)alloc((size_t)HIDDEN * NUM_GRAPHS * 4);
    int*   gstart     = (int*)alloc((size_t)(NUM_GRAPHS + 1) * 4);

    hipMemsetAsync(counts, 0, (size_t)N_NODES * 4, stream);
    hipMemsetAsync(pooledT, 0, (size_t)HIDDEN * NUM_GRAPHS * 4, stream);

    convert_wt_kernel<<<dim3(HIDDEN, 6), 256, 0, stream>>>(Wg, Wl, WT);
    gather_kernel<<<N_NODES, 256, 0, stream>>>(nodes, emb, bufA);
    hist_kernel<<<(E_TOTAL + 255) / 256, 256, 0, stream>>>(ei, counts);
    scan_kernel<<<1, 1024, 0, stream>>>(counts, row_ptr, cursor);
    scatter_kernel<<<(E_TOTAL + 255) / 256, 256, 0, stream>>>(ei, cursor, src_sorted);

    _Float16* cur = bufA;
    _Float16* oth = bufB;
    for (int l = 0; l < 3; l++) {
        gemm_f16_kernel<<<N_NODES / 128, 256, 0, stream>>>(
            cur, WT + (size_t)l * HIDDEN * HIDDEN, nullptr, oth,
            a_src + (size_t)l * HIDDEN, a_dst + (size_t)l * HIDDEN, es, ed);
        stats_kernel<<<N_NODES / 4, 256, 0, stream>>>(
            row_ptr, src_sorted, es, ed, epack, dinv);
        slice_agg_kernel<<<dim3(8, N_NODES / 4), 256, 0, stream>>>(
            oth, row_ptr, epack, dinv, bg + (size_t)l * HIDDEN, cur);
        gemm_f16_kernel<<<N_NODES / 128, 256, 0, stream>>>(
            cur, WT + (size_t)(3 + l) * HIDDEN * HIDDEN, bl + (size_t)l * HIDDEN, oth,
            nullptr, nullptr, nullptr, nullptr);
        _Float16* t = cur; cur = oth; oth = t;
    }

    graph_bounds_kernel<<<1, 128, 0, stream>>>(batch, gstart);
    pool_partial_kernel<<<dim3(NUM_GRAPHS, POOL_SPLITS), 256, 0, stream>>>(cur, gstart, pooledT);
    mean_kernel<<<(HIDDEN * NUM_GRAPHS) / 256, 256, 0, stream>>>(pooledT, gstart, meanT);
    final_kernel<<<dim3((VOCAB + 255) / 256, FINAL_GSPLIT), 256, 0, stream>>>(meanT, Wout, bout, out);
}

// Round 9
// 850.943 us; speedup vs baseline: 1.7760x; 1.7760x over previous
//
#include <hip/hip_runtime.h>

#define N_NODES 65536
#define N_EDGES 1048576
#define E_TOTAL (N_EDGES + N_NODES)
#define VOCAB 50000
#define HIDDEN 256
#define NUM_GRAPHS 64
#define NEG_SLOPE 0.2f
#define SM_EPS 1e-16f

typedef _Float16 f16x8 __attribute__((ext_vector_type(8)));
typedef _Float16 f16x4 __attribute__((ext_vector_type(4)));
typedef float f32x4 __attribute__((ext_vector_type(4)));

// ---------------- gather: x = (fp16) emb[nodes] ----------------
__global__ __launch_bounds__(256) void gather_kernel(const int* __restrict__ nodes,
    const float* __restrict__ emb, _Float16* __restrict__ x) {
    int i = blockIdx.x;
    int t = threadIdx.x;
    x[(size_t)i * HIDDEN + t] = (_Float16)emb[(size_t)nodes[i] * HIDDEN + t];
}

// ---------------- weight transpose+convert: WT[mat][n][k] = (fp16) W[mat][k][n] ----------------
__global__ __launch_bounds__(256) void convert_wt_kernel(const float* __restrict__ Wg,
    const float* __restrict__ Wl, _Float16* __restrict__ WT) {
    int mat = blockIdx.y;
    int n = blockIdx.x;
    int k = threadIdx.x;
    const float* W = (mat < 3) ? (Wg + (size_t)mat * HIDDEN * HIDDEN)
                               : (Wl + (size_t)(mat - 3) * HIDDEN * HIDDEN);
    WT[(size_t)mat * HIDDEN * HIDDEN + (size_t)n * HIDDEN + k] = (_Float16)W[(size_t)k * HIDDEN + n];
}

// ---------------- CSR build (by dst) ----------------
__global__ __launch_bounds__(256) void hist_kernel(const int* __restrict__ ei, int* __restrict__ counts) {
    int e = blockIdx.x * 256 + threadIdx.x;
    if (e >= E_TOTAL) return;
    int dst = (e < N_EDGES) ? ei[N_EDGES + e] : (e - N_EDGES);
    atomicAdd(&counts[dst], 1);
}

__global__ __launch_bounds__(1024) void scan_kernel(const int* __restrict__ counts,
    int* __restrict__ row_ptr, int* __restrict__ cursor) {
    __shared__ int sp[1024];
    int t = threadIdx.x;
    int base = t * 64;
    int s = 0;
    for (int i = 0; i < 64; i++) s += counts[base + i];
    sp[t] = s;
    __syncthreads();
    for (int d = 1; d < 1024; d <<= 1) {
        int v = (t >= d) ? sp[t - d] : 0;
        __syncthreads();
        sp[t] += v;
        __syncthreads();
    }
    int run = sp[t] - s;
    for (int i = 0; i < 64; i++) {
        int c = counts[base + i];
        row_ptr[base + i] = run;
        cursor[base + i] = run;
        run += c;
    }
    if (t == 1023) row_ptr[N_NODES] = run;
}

__global__ __launch_bounds__(256) void scatter_kernel(const int* __restrict__ ei,
    int* __restrict__ cursor, int* __restrict__ src_sorted) {
    int e = blockIdx.x * 256 + threadIdx.x;
    if (e >= E_TOTAL) return;
    int src, dst;
    if (e < N_EDGES) { src = ei[e]; dst = ei[N_EDGES + e]; }
    else             { src = dst = e - N_EDGES; }
    int pos = atomicAdd(&cursor[dst], 1);
    src_sorted[pos] = src;
}

// ---------------- fp16 MFMA GEMM: BM=128, BN=128, BK=32, 1024 blocks (4/CU) ----
// C[M,256] = A[M,256] @ W (WT[n][k]). Grid (M/128, 2); blockIdx.y picks the
// 128-col half. FUSED: partial row-dots vs a_s/a_d atomicAdd'ed into es/ed
// (caller zeroes es/ed first). Template tag -> distinct mangled names in prof.
#define PAD_K 40
template <bool FUSED>
__global__ __launch_bounds__(256) void gemm_f16_kernel(const _Float16* __restrict__ A,
    const _Float16* __restrict__ WT, const float* __restrict__ bias,
    _Float16* __restrict__ C,
    const float* __restrict__ a_s, const float* __restrict__ a_d,
    float* __restrict__ es, float* __restrict__ ed) {
    __shared__ _Float16 As[128][PAD_K];   // 10240 B
    __shared__ _Float16 Bs[128][PAD_K];   // 10240 B
    int tid = threadIdx.x;
    int wave = tid >> 6;
    int lane = tid & 63;
    int quad = lane >> 4;
    int l16 = lane & 15;
    int m0 = blockIdx.x * 128;
    int n0 = blockIdx.y * 128;

    f32x4 acc[2][8];
    #pragma unroll
    for (int rt = 0; rt < 2; rt++)
        #pragma unroll
        for (int ct = 0; ct < 8; ct++)
            acc[rt][ct] = (f32x4){0.f, 0.f, 0.f, 0.f};

    for (int k0 = 0; k0 < HIDDEN; k0 += 32) {
        __syncthreads();
        // stage A: 128 rows x 32 halfs = 512 16B-chunks; 2 per thread
        #pragma unroll
        for (int i = 0; i < 2; i++) {
            int c = tid + i * 256;
            int row = c >> 2, q = c & 3;
            *(f16x8*)&As[row][q * 8] =
                *(const f16x8*)(A + (size_t)(m0 + row) * HIDDEN + k0 + q * 8);
        }
        // stage B: 128 rows (cols n0..n0+127) x 32 halfs; 2 per thread
        #pragma unroll
        for (int i = 0; i < 2; i++) {
            int c = tid + i * 256;
            int row = c >> 2, q = c & 3;
            *(f16x8*)&Bs[row][q * 8] =
                *(const f16x8*)(WT + (size_t)(n0 + row) * HIDDEN + k0 + q * 8);
        }
        __syncthreads();
        f16x8 a0 = *(const f16x8*)&As[wave * 32 + l16][quad * 8];
        f16x8 a1 = *(const f16x8*)&As[wave * 32 + 16 + l16][quad * 8];
        #pragma unroll
        for (int ct = 0; ct < 8; ct++) {
            f16x8 b = *(const f16x8*)&Bs[ct * 16 + l16][quad * 8];
            acc[0][ct] = __builtin_amdgcn_mfma_f32_16x16x32_f16(a0, b, acc[0][ct], 0, 0, 0);
            acc[1][ct] = __builtin_amdgcn_mfma_f32_16x16x32_f16(a1, b, acc[1][ct], 0, 0, 0);
        }
    }
    // epilogue: C/D layout col=lane&15, row=quad*4+reg
    #pragma unroll
    for (int rt = 0; rt < 2; rt++) {
        #pragma unroll
        for (int ct = 0; ct < 8; ct++) {
            int col = n0 + ct * 16 + l16;
            float bv = (bias != nullptr) ? bias[col] : 0.f;
            int rowbase = m0 + wave * 32 + rt * 16 + quad * 4;
            #pragma unroll
            for (int r = 0; r < 4; r++) {
                C[(size_t)(rowbase + r) * HIDDEN + col] = (_Float16)(acc[rt][ct][r] + bv);
            }
        }
    }
    // fused dots: partial over this block's 128 cols, atomicAdd into es/ed
    if (FUSED) {
        #pragma unroll
        for (int rt = 0; rt < 2; rt++) {
            float ds0 = 0.f, ds1 = 0.f, ds2 = 0.f, ds3 = 0.f;
            float dd0 = 0.f, dd1 = 0.f, dd2 = 0.f, dd3 = 0.f;
            #pragma unroll
            for (int ct = 0; ct < 8; ct++) {
                int col = n0 + ct * 16 + l16;
                float av = a_s[col];
                float dv = a_d[col];
                ds0 += acc[rt][ct][0] * av; dd0 += acc[rt][ct][0] * dv;
                ds1 += acc[rt][ct][1] * av; dd1 += acc[rt][ct][1] * dv;
                ds2 += acc[rt][ct][2] * av; dd2 += acc[rt][ct][2] * dv;
                ds3 += acc[rt][ct][3] * av; dd3 += acc[rt][ct][3] * dv;
            }
            #pragma unroll
            for (int off = 1; off < 16; off <<= 1) {
                ds0 += __shfl_xor(ds0, off); dd0 += __shfl_xor(dd0, off);
                ds1 += __shfl_xor(ds1, off); dd1 += __shfl_xor(dd1, off);
                ds2 += __shfl_xor(ds2, off); dd2 += __shfl_xor(dd2, off);
                ds3 += __shfl_xor(ds3, off); dd3 += __shfl_xor(dd3, off);
            }
            if (l16 == 0) {
                int rowbase = m0 + wave * 32 + rt * 16 + quad * 4;
                atomicAdd(&es[rowbase + 0], ds0); atomicAdd(&ed[rowbase + 0], dd0);
                atomicAdd(&es[rowbase + 1], ds1); atomicAdd(&ed[rowbase + 1], dd1);
                atomicAdd(&es[rowbase + 2], ds2); atomicAdd(&ed[rowbase + 2], dd2);
                atomicAdd(&es[rowbase + 3], ds3); atomicAdd(&ed[rowbase + 3], dd3);
            }
        }
    }
}

// ---------------- wave-per-dst segment softmax + weighted aggregate (fp16 h) ----------------
// R6-best structure: pass1 e->wbuf+max, pass1b w=exp->wbuf+denom, pass2 unroll x4.
__global__ __launch_bounds__(256) void agg_kernel(const _Float16* __restrict__ h,
    const int* __restrict__ row_ptr, const int* __restrict__ src_sorted,
    const float* __restrict__ es, const float* __restrict__ ed,
    const float* __restrict__ bg, float* __restrict__ wbuf, _Float16* __restrict__ g) {
    int gtid = blockIdx.x * 256 + threadIdx.x;
    int dst = gtid >> 6;
    int lane = threadIdx.x & 63;
    if (dst >= N_NODES) return;
    int start = row_ptr[dst];
    int end = row_ptr[dst + 1];
    float edd = ed[dst];

    float m = -1e30f;
    for (int i = start + lane; i < end; i += 64) {
        float e = es[src_sorted[i]] + edd;
        e = (e > 0.f) ? e : NEG_SLOPE * e;
        wbuf[i] = e;
        m = fmaxf(m, e);
    }
    for (int off = 32; off; off >>= 1) m = fmaxf(m, __shfl_xor(m, off));

    float denom = 0.f;
    for (int i = start + lane; i < end; i += 64) {
        float w = __expf(wbuf[i] - m);
        wbuf[i] = w;
        denom += w;
    }
    for (int off = 32; off; off >>= 1) denom += __shfl_xor(denom, off);
    float inv = 1.0f / (denom + SM_EPS);

    float4 acc = make_float4(0.f, 0.f, 0.f, 0.f);
    int i = start;
    for (; i + 3 < end; i += 4) {
        int s0 = src_sorted[i + 0];
        int s1 = src_sorted[i + 1];
        int s2 = src_sorted[i + 2];
        int s3 = src_sorted[i + 3];
        float a0 = wbuf[i + 0] * inv;
        float a1 = wbuf[i + 1] * inv;
        float a2 = wbuf[i + 2] * inv;
        float a3 = wbuf[i + 3] * inv;
        f16x4 r0 = *(const f16x4*)(h + (size_t)s0 * HIDDEN + lane * 4);
        f16x4 r1 = *(const f16x4*)(h + (size_t)s1 * HIDDEN + lane * 4);
        f16x4 r2 = *(const f16x4*)(h + (size_t)s2 * HIDDEN + lane * 4);
        f16x4 r3 = *(const f16x4*)(h + (size_t)s3 * HIDDEN + lane * 4);
        acc.x += a0 * (float)r0[0] + a1 * (float)r1[0] + a2 * (float)r2[0] + a3 * (float)r3[0];
        acc.y += a0 * (float)r0[1] + a1 * (float)r1[1] + a2 * (float)r2[1] + a3 * (float)r3[1];
        acc.z += a0 * (float)r0[2] + a1 * (float)r1[2] + a2 * (float)r2[2] + a3 * (float)r3[2];
        acc.w += a0 * (float)r0[3] + a1 * (float)r1[3] + a2 * (float)r2[3] + a3 * (float)r3[3];
    }
    for (; i < end; i++) {
        int s0 = src_sorted[i];
        float a0 = wbuf[i] * inv;
        f16x4 r0 = *(const f16x4*)(h + (size_t)s0 * HIDDEN + lane * 4);
        acc.x += a0 * (float)r0[0];
        acc.y += a0 * (float)r0[1];
        acc.z += a0 * (float)r0[2];
        acc.w += a0 * (float)r0[3];
    }
    float4 b4 = *(const float4*)(bg + lane * 4);
    f16x4 outv;
    outv[0] = (_Float16)fmaxf(acc.x + b4.x, 0.f);
    outv[1] = (_Float16)fmaxf(acc.y + b4.y, 0.f);
    outv[2] = (_Float16)fmaxf(acc.z + b4.z, 0.f);
    outv[3] = (_Float16)fmaxf(acc.w + b4.w, 0.f);
    *(f16x4*)(g + (size_t)dst * HIDDEN + lane * 4) = outv;
}

// ---------------- graph boundaries: batch is SORTED -> binary search ----------------
__global__ __launch_bounds__(128) void graph_bounds_kernel(const int* __restrict__ batch,
    int* __restrict__ gstart) {
    int g = threadIdx.x;
    if (g > NUM_GRAPHS) return;
    if (g == NUM_GRAPHS) { gstart[NUM_GRAPHS] = N_NODES; return; }
    int lo = 0, hi = N_NODES;
    while (lo < hi) {
        int mid = (lo + hi) >> 1;
        if (batch[mid] < g) lo = mid + 1; else hi = mid;
    }
    gstart[g] = lo;
}

// ---------------- mean pool: owner-computes partial reduction (fp16 x) ----------------
#define POOL_SPLITS 16
__global__ __launch_bounds__(256) void pool_partial_kernel(const _Float16* __restrict__ x,
    const int* __restrict__ gstart, float* __restrict__ pooledT) {
    int g = blockIdx.x;
    int chunk = blockIdx.y;
    int t = threadIdx.x;
    int s = gstart[g];
    int e = gstart[g + 1];
    int n = e - s;
    int per = (n + POOL_SPLITS - 1) / POOL_SPLITS;
    int r0 = s + chunk * per;
    int r1 = min(r0 + per, e);
    if (r0 >= r1) return;
    float acc = 0.f;
    for (int r = r0; r < r1; r++) acc += (float)x[(size_t)r * HIDDEN + t];
    atomicAdd(&pooledT[t * NUM_GRAPHS + g], acc);
}

__global__ __launch_bounds__(256) void mean_kernel(const float* __restrict__ pooledT,
    const int* __restrict__ gstart, float* __restrict__ meanT) {
    int i = blockIdx.x * 256 + threadIdx.x;
    int g = i & (NUM_GRAPHS - 1);
    float c = (float)max(gstart[g + 1] - gstart[g], 1);
    meanT[i] = pooledT[i] / c;
}

// ---------------- final: out[64,50000] = pooled @ Wout + bout (fp32) ----------------
#define FINAL_GSPLIT 4
#define G_PER (NUM_GRAPHS / FINAL_GSPLIT)
__global__ __launch_bounds__(256) void final_kernel(const float* __restrict__ meanT,
    const float* __restrict__ Wout, const float* __restrict__ bout, float* __restrict__ out) {
    int j = blockIdx.x * 256 + threadIdx.x;
    int g0 = blockIdx.y * G_PER;
    if (j >= VOCAB) return;
    float acc[G_PER];
    #pragma unroll
    for (int g = 0; g < G_PER; g++) acc[g] = 0.f;
    #pragma unroll 4
    for (int k = 0; k < HIDDEN; k++) {
        float w = Wout[(size_t)k * VOCAB + j];
        #pragma unroll
        for (int g = 0; g < G_PER; g++) acc[g] += meanT[k * NUM_GRAPHS + g0 + g] * w;
    }
    float b = bout[j];
    #pragma unroll
    for (int g = 0; g < G_PER; g++) out[(size_t)(g0 + g) * VOCAB + j] = acc[g] + b;
}

extern "C" void kernel_launch(void* const* d_in, const int* in_sizes, int n_in,
                              void* d_out, int out_size, void* d_ws, size_t ws_size,
                              hipStream_t stream) {
    const int*   nodes = (const int*)d_in[0];
    const int*   ei    = (const int*)d_in[1];
    const int*   batch = (const int*)d_in[2];
    const float* emb   = (const float*)d_in[3];
    const float* Wg    = (const float*)d_in[4];
    const float* a_src = (const float*)d_in[5];
    const float* a_dst = (const float*)d_in[6];
    const float* bg    = (const float*)d_in[7];
    const float* Wl    = (const float*)d_in[8];
    const float* bl    = (const float*)d_in[9];
    const float* Wout  = (const float*)d_in[10];
    const float* bout  = (const float*)d_in[11];
    float* out = (float*)d_out;

    char* ws = (char*)d_ws;
    size_t off = 0;
    auto alloc = [&](size_t bytes) -> void* {
        void* p = ws + off;
        off += (bytes + 255) & ~(size_t)255;
        return p;
    };
    _Float16* bufA    = (_Float16*)alloc((size_t)N_NODES * HIDDEN * 2);
    _Float16* bufB    = (_Float16*)alloc((size_t)N_NODES * HIDDEN * 2);
    _Float16* WT      = (_Float16*)alloc((size_t)6 * HIDDEN * HIDDEN * 2);
    float* es         = (float*)alloc((size_t)N_NODES * 4);
    float* ed         = (float*)alloc((size_t)N_NODES * 4);
    int*   counts     = (int*)alloc((size_t)N_NODES * 4);
    int*   row_ptr    = (int*)alloc((size_t)(N_NODES + 1) * 4);
    int*   cursor     = (int*)alloc((size_t)N_NODES * 4);
    int*   src_sorted = (int*)alloc((size_t)E_TOTAL * 4);
    float* wbuf       = (float*)alloc((size_t)E_TOTAL * 4);
    float* pooledT    = (float*)alloc((size_t)HIDDEN * NUM_GRAPHS * 4);
    float* meanT      = (float*)alloc((size_t)HIDDEN * NUM_GRAPHS * 4);
    int*   gstart     = (int*)alloc((size_t)(NUM_GRAPHS + 1) * 4);

    hipMemsetAsync(counts, 0, (size_t)N_NODES * 4, stream);
    hipMemsetAsync(pooledT, 0, (size_t)HIDDEN * NUM_GRAPHS * 4, stream);

    convert_wt_kernel<<<dim3(HIDDEN, 6), 256, 0, stream>>>(Wg, Wl, WT);
    gather_kernel<<<N_NODES, 256, 0, stream>>>(nodes, emb, bufA);
    hist_kernel<<<(E_TOTAL + 255) / 256, 256, 0, stream>>>(ei, counts);
    scan_kernel<<<1, 1024, 0, stream>>>(counts, row_ptr, cursor);
    scatter_kernel<<<(E_TOTAL + 255) / 256, 256, 0, stream>>>(ei, cursor, src_sorted);

    _Float16* cur = bufA;
    _Float16* oth = bufB;
    for (int l = 0; l < 3; l++) {
        // zero es/ed for the fused-partial atomics
        hipMemsetAsync(es, 0, (size_t)N_NODES * 4, stream);
        hipMemsetAsync(ed, 0, (size_t)N_NODES * 4, stream);
        gemm_f16_kernel<true><<<dim3(N_NODES / 128, 2), 256, 0, stream>>>(
            cur, WT + (size_t)l * HIDDEN * HIDDEN, nullptr, oth,
            a_src + (size_t)l * HIDDEN, a_dst + (size_t)l * HIDDEN, es, ed);
        agg_kernel<<<N_NODES / 4, 256, 0, stream>>>(
            oth, row_ptr, src_sorted, es, ed, bg + (size_t)l * HIDDEN, wbuf, cur);
        gemm_f16_kernel<false><<<dim3(N_NODES / 128, 2), 256, 0, stream>>>(
            cur, WT + (size_t)(3 + l) * HIDDEN * HIDDEN, bl + (size_t)l * HIDDEN, oth,
            nullptr, nullptr, nullptr, nullptr);
        _Float16* t = cur; cur = oth; oth = t;
    }

    graph_bounds_kernel<<<1, 128, 0, stream>>>(batch, gstart);
    pool_partial_kernel<<<dim3(NUM_GRAPHS, POOL_SPLITS), 256, 0, stream>>>(cur, gstart, pooledT);
    mean_kernel<<<(HIDDEN * NUM_GRAPHS) / 256, 256, 0, stream>>>(pooledT, gstart, meanT);
    final_kernel<<<dim3((VOCAB + 255) / 256, FINAL_GSPLIT), 256, 0, stream>>>(meanT, Wout, bout, out);
}